// Round 2
// baseline (375.151 us; speedup 1.0000x reference)
//
#include <hip/hip_runtime.h>
#include <hip/hip_bf16.h>

// Problem constants (from reference)
#define BATCH   16
#define TT      512
#define CC      768
#define D_IN    3072
#define HIDDEN  1024
#define LL      255          // (T - 4)/2 + 1
#define OUTROWS 257
#define KSTACK  12288        // D_IN * 4

typedef float f32x4 __attribute__((ext_vector_type(4)));
typedef __bf16 bf16x8 __attribute__((ext_vector_type(8)));
typedef unsigned short u16;

// round-to-nearest-even f32 -> bf16 bits
__device__ __forceinline__ u16 f2bf(float f) {
    unsigned u = __builtin_bit_cast(unsigned, f);
    u = (u + 0x7FFFu + ((u >> 16) & 1u)) >> 16;
    return (u16)u;
}

__device__ __forceinline__ bf16x8 lds_read8(const u16* p) {
    return __builtin_bit_cast(bf16x8, *(const uint4*)p);
}

// ---------------- W_stack f32 -> bf16 ----------------
__global__ __launch_bounds__(256) void cvt_wstack(const float* __restrict__ W, u16* __restrict__ out) {
    size_t i = ((size_t)blockIdx.x * 256 + threadIdx.x) * 4;
    size_t stride = (size_t)gridDim.x * 256 * 4;
    for (; i < (size_t)HIDDEN * KSTACK; i += stride) {
        float4 v = *(const float4*)(W + i);
        ushort4 o = make_ushort4(f2bf(v.x), f2bf(v.y), f2bf(v.z), f2bf(v.w));
        *(ushort4*)(out + i) = o;
    }
}

// ---------------- GEMM1: x1 = gelu(spikes @ W_embed[date]^T + b_embed) * 32 ----------------
// M=512, N=3072, K=768 per batch. Tile 128x128, BK=64, 4 waves (2x2), each wave 64x64.
__global__ __launch_bounds__(256) void gemm1(const float* __restrict__ spikes,
                                             const float* __restrict__ W_embed,
                                             const float* __restrict__ b_embed,
                                             const int* __restrict__ date_idx,
                                             u16* __restrict__ x1) {
    const int m0 = blockIdx.x * 128;   // t
    const int n0 = blockIdx.y * 128;   // d
    const int bb = blockIdx.z;
    const int date = date_idx[bb];
    const float* A  = spikes  + (size_t)bb  * TT * CC;
    const float* Bw = W_embed + (size_t)date * D_IN * CC;

    __shared__ u16 As[128 * 64];
    __shared__ u16 Bs[128 * 64];

    const int tid  = threadIdx.x;
    const int lane = tid & 63;
    const int wave = tid >> 6;
    const int wm = wave >> 1, wn = wave & 1;

    f32x4 acc[4][4] = {};

    for (int k0 = 0; k0 < CC; k0 += 64) {
        // stage A,B: 128 rows x 64 cols f32 -> bf16 swizzled LDS
        {
            const int c4 = tid & 15;          // float4 column
            int r = tid >> 4;                 // row, 16 rows/pass, 8 passes
            #pragma unroll
            for (int p = 0; p < 8; ++p, r += 16) {
                float4 va = *(const float4*)(A  + (size_t)(m0 + r) * CC + k0 + c4 * 4);
                float4 vb = *(const float4*)(Bw + (size_t)(n0 + r) * CC + k0 + c4 * 4);
                const int col = c4 * 4;                       // bf16 units
                const int idx = r * 64 + (col ^ ((r & 7) << 3));
                *(ushort4*)(&As[idx]) = make_ushort4(f2bf(va.x), f2bf(va.y), f2bf(va.z), f2bf(va.w));
                *(ushort4*)(&Bs[idx]) = make_ushort4(f2bf(vb.x), f2bf(vb.y), f2bf(vb.z), f2bf(vb.w));
            }
        }
        __syncthreads();
        #pragma unroll
        for (int kk = 0; kk < 64; kk += 32) {
            bf16x8 af[4], bfr[4];
            const int krow = lane & 15;
            const int kcol = kk + ((lane >> 4) << 3);  // bf16 units
            #pragma unroll
            for (int i = 0; i < 4; ++i) {
                const int ra = wm * 64 + i * 16 + krow;
                af[i]  = lds_read8(&As[ra * 64 + (kcol ^ ((ra & 7) << 3))]);
                const int rb = wn * 64 + i * 16 + krow;
                bfr[i] = lds_read8(&Bs[rb * 64 + (kcol ^ ((rb & 7) << 3))]);
            }
            #pragma unroll
            for (int i = 0; i < 4; ++i)
                #pragma unroll
                for (int j = 0; j < 4; ++j)
                    acc[i][j] = __builtin_amdgcn_mfma_f32_16x16x32_bf16(af[i], bfr[j], acc[i][j], 0, 0, 0);
        }
        __syncthreads();
    }

    // epilogue: + b_embed, exact gelu, * 32, store bf16
    const float* be = b_embed + (size_t)date * D_IN;
    #pragma unroll
    for (int i = 0; i < 4; ++i) {
        #pragma unroll
        for (int j = 0; j < 4; ++j) {
            const int col  = n0 + wn * 64 + j * 16 + (lane & 15);
            const float bias = be[col];
            const int rbase = m0 + wm * 64 + i * 16 + ((lane >> 4) << 2);
            #pragma unroll
            for (int q = 0; q < 4; ++q) {
                float v = acc[i][j][q] + bias;
                float g = 0.5f * v * (1.0f + erff(v * 0.70710678118654752f)) * 32.0f;
                x1[(size_t)bb * TT * D_IN + (size_t)(rbase + q) * D_IN + col] = f2bf(g);
            }
        }
    }
}

// ---------------- GEMM2: out = stacked @ W_stack^T + b_stack + pos_table[ts] ----------------
// per batch M=255 (pad to 256), N=1024, K=12288. stacked[l, s*3072+d] = x1[2l+s, d].
__global__ __launch_bounds__(256) void gemm2(const u16* __restrict__ x1,
                                             const u16* __restrict__ Wbf,
                                             const float* __restrict__ b_stack,
                                             const float* __restrict__ pos_table,
                                             const int* __restrict__ tstamp,
                                             float* __restrict__ out) {
    const int l0 = blockIdx.x * 128;   // window row tile (0 or 128)
    const int n0 = blockIdx.y * 128;
    const int bb = blockIdx.z;
    const u16* Xb = x1 + (size_t)bb * TT * D_IN;

    __shared__ u16 As[128 * 64];
    __shared__ u16 Bs[128 * 64];

    const int tid  = threadIdx.x;
    const int lane = tid & 63;
    const int wave = tid >> 6;
    const int wm = wave >> 1, wn = wave & 1;

    f32x4 acc[4][4] = {};

    for (int k0 = 0; k0 < KSTACK; k0 += 64) {
        const int s  = k0 / D_IN;       // which window slot (64 | 3072, never straddles)
        const int d0 = k0 % D_IN;
        {
            // 128 rows x 64 cols bf16: 8 chunks of 8 bf16 per row, 32 rows/pass, 4 passes
            const int c = tid & 7;      // 16B chunk (8 bf16)
            int r = tid >> 3;           // row, 32 rows/pass
            #pragma unroll
            for (int p = 0; p < 4; ++p, r += 32) {
                int gl = l0 + r; if (gl > LL - 1) gl = LL - 1;     // clamp pad rows
                uint4 va = *(const uint4*)(Xb + (size_t)(2 * gl + s) * D_IN + d0 + c * 8);
                uint4 vb = *(const uint4*)(Wbf + (size_t)(n0 + r) * KSTACK + k0 + c * 8);
                const int col = c * 8;
                const int idx = r * 64 + (col ^ ((r & 7) << 3));
                *(uint4*)(&As[idx]) = va;
                *(uint4*)(&Bs[idx]) = vb;
            }
        }
        __syncthreads();
        #pragma unroll
        for (int kk = 0; kk < 64; kk += 32) {
            bf16x8 af[4], bfr[4];
            const int krow = lane & 15;
            const int kcol = kk + ((lane >> 4) << 3);
            #pragma unroll
            for (int i = 0; i < 4; ++i) {
                const int ra = wm * 64 + i * 16 + krow;
                af[i]  = lds_read8(&As[ra * 64 + (kcol ^ ((ra & 7) << 3))]);
                const int rb = wn * 64 + i * 16 + krow;
                bfr[i] = lds_read8(&Bs[rb * 64 + (kcol ^ ((rb & 7) << 3))]);
            }
            #pragma unroll
            for (int i = 0; i < 4; ++i)
                #pragma unroll
                for (int j = 0; j < 4; ++j)
                    acc[i][j] = __builtin_amdgcn_mfma_f32_16x16x32_bf16(af[i], bfr[j], acc[i][j], 0, 0, 0);
        }
        __syncthreads();
    }

    // epilogue: + b_stack + pos_table[ts], write f32 rows 2..256
    #pragma unroll
    for (int i = 0; i < 4; ++i) {
        #pragma unroll
        for (int j = 0; j < 4; ++j) {
            const int col = n0 + wn * 64 + j * 16 + (lane & 15);
            const int lb  = l0 + wm * 64 + i * 16 + ((lane >> 4) << 2);
            #pragma unroll
            for (int q = 0; q < 4; ++q) {
                const int l = lb + q;
                if (l < LL) {
                    const int tsv = tstamp[bb * TT + l];
                    float v = acc[i][j][q] + b_stack[col] + pos_table[(size_t)tsv * HIDDEN + col];
                    out[(size_t)bb * OUTROWS * HIDDEN + (size_t)(2 + l) * HIDDEN + col] = v;
                }
            }
        }
    }
}

// ---------------- rows 0/1 + mask + ts outputs ----------------
__global__ __launch_bounds__(256) void epilogue_misc(const int* __restrict__ smask,
                                                     const int* __restrict__ tstamp,
                                                     const int* __restrict__ mask_idx_p,
                                                     const int* __restrict__ session_idx_p,
                                                     const float* __restrict__ prompt_table,
                                                     const float* __restrict__ session_table,
                                                     float* __restrict__ out) {
    const int bb = blockIdx.x;
    const int tid = threadIdx.x;
    const int mi = mask_idx_p[0];
    const int si = session_idx_p[0];
    float* xb = out + (size_t)bb * OUTROWS * HIDDEN;
    for (int i = tid; i < HIDDEN; i += 256) {
        xb[i]          = session_table[(size_t)si * HIDDEN + i];
        xb[HIDDEN + i] = prompt_table[(size_t)mi * HIDDEN + i];
    }
    float* maskout = out + (size_t)BATCH * OUTROWS * HIDDEN + (size_t)bb * OUTROWS;
    float* tsout   = out + (size_t)BATCH * OUTROWS * HIDDEN + (size_t)BATCH * OUTROWS + (size_t)bb * OUTROWS;
    for (int j = tid; j < OUTROWS; j += 256) {
        if (j == 0)      { maskout[0] = 1.0f; tsout[0] = 0.0f; }
        else if (j == 1) { maskout[1] = 1.0f; tsout[1] = 1.0f; }
        else {
            const int l = j - 2;
            int m = 1;
            #pragma unroll
            for (int s = 0; s < 4; ++s) m *= smask[bb * TT + 2 * l + s];
            maskout[j] = (float)m;
            tsout[j]   = (float)(tstamp[bb * TT + l] + 2);
        }
    }
}

extern "C" void kernel_launch(void* const* d_in, const int* in_sizes, int n_in,
                              void* d_out, int out_size, void* d_ws, size_t ws_size,
                              hipStream_t stream) {
    const float* spikes      = (const float*)d_in[0];
    const int*   spikes_mask = (const int*)d_in[1];
    const int*   tstamp      = (const int*)d_in[2];
    const int*   date_idx    = (const int*)d_in[3];
    const int*   mask_idx    = (const int*)d_in[4];
    const int*   session_idx = (const int*)d_in[5];
    const float* W_embed     = (const float*)d_in[6];
    const float* b_embed     = (const float*)d_in[7];
    const float* W_stack     = (const float*)d_in[8];
    const float* b_stack     = (const float*)d_in[9];
    const float* pos_table   = (const float*)d_in[10];
    const float* prompt_tab  = (const float*)d_in[11];
    const float* session_tab = (const float*)d_in[12];
    float* out = (float*)d_out;

    // workspace layout: x1 bf16 (16*512*3072*2 = 50,331,648 B), W_stack bf16 (25,165,824 B)
    u16* x1  = (u16*)d_ws;
    u16* Wbf = (u16*)((char*)d_ws + (size_t)BATCH * TT * D_IN * 2);

    cvt_wstack<<<2048, 256, 0, stream>>>(W_stack, Wbf);
    gemm1<<<dim3(TT / 128, D_IN / 128, BATCH), 256, 0, stream>>>(spikes, W_embed, b_embed, date_idx, x1);
    gemm2<<<dim3(2, HIDDEN / 128, BATCH), 256, 0, stream>>>(x1, Wbf, b_stack, pos_table, tstamp, out);
    epilogue_misc<<<BATCH, 256, 0, stream>>>(spikes_mask, tstamp, mask_idx, session_idx,
                                             prompt_tab, session_tab, out);
}

// Round 3
// 339.679 us; speedup vs baseline: 1.1044x; 1.1044x over previous
//
#include <hip/hip_runtime.h>
#include <hip/hip_bf16.h>

// Problem constants (from reference)
#define BATCH   16
#define TT      512
#define CC      768
#define D_IN    3072
#define HIDDEN  1024
#define LL      255          // (T - 4)/2 + 1
#define OUTROWS 257
#define KSTACK  12288        // D_IN * 4

typedef float f32x4 __attribute__((ext_vector_type(4)));
typedef __bf16 bf16x8 __attribute__((ext_vector_type(8)));
typedef unsigned short u16;

// round-to-nearest-even f32 -> bf16 bits
__device__ __forceinline__ u16 f2bf(float f) {
    unsigned u = __builtin_bit_cast(unsigned, f);
    u = (u + 0x7FFFu + ((u >> 16) & 1u)) >> 16;
    return (u16)u;
}

__device__ __forceinline__ bf16x8 lds_read8(const u16* p) {
    return __builtin_bit_cast(bf16x8, *(const uint4*)p);
}

// async global->LDS, 16B per lane. LDS dest is wave-uniform base (+lane*16 by HW),
// global src is per-lane.
__device__ __forceinline__ void gload16(const u16* g, u16* l) {
    __builtin_amdgcn_global_load_lds(
        (const __attribute__((address_space(1))) void*)g,
        (__attribute__((address_space(3))) void*)l, 16, 0, 0);
}

// ---------------- W_stack f32 -> bf16 ----------------
__global__ __launch_bounds__(256) void cvt_wstack(const float* __restrict__ W, u16* __restrict__ out) {
    size_t i = ((size_t)blockIdx.x * 256 + threadIdx.x) * 4;
    size_t stride = (size_t)gridDim.x * 256 * 4;
    for (; i < (size_t)HIDDEN * KSTACK; i += stride) {
        float4 v = *(const float4*)(W + i);
        ushort4 o = make_ushort4(f2bf(v.x), f2bf(v.y), f2bf(v.z), f2bf(v.w));
        *(ushort4*)(out + i) = o;
    }
}

// ---------------- GEMM1: x1 = gelu(spikes @ W_embed[date]^T + b_embed) * 32 ----------------
// M=512, N=3072, K=768 per batch. Tile 128x128, BK=64, 4 waves (2x2), each wave 64x64.
__global__ __launch_bounds__(256) void gemm1(const float* __restrict__ spikes,
                                             const float* __restrict__ W_embed,
                                             const float* __restrict__ b_embed,
                                             const int* __restrict__ date_idx,
                                             u16* __restrict__ x1) {
    const int m0 = blockIdx.x * 128;   // t
    const int n0 = blockIdx.y * 128;   // d
    const int bb = blockIdx.z;
    const int date = date_idx[bb];
    const float* A  = spikes  + (size_t)bb  * TT * CC;
    const float* Bw = W_embed + (size_t)date * D_IN * CC;

    __shared__ u16 As[128 * 64];
    __shared__ u16 Bs[128 * 64];

    const int tid  = threadIdx.x;
    const int lane = tid & 63;
    const int wave = tid >> 6;
    const int wm = wave >> 1, wn = wave & 1;

    f32x4 acc[4][4] = {};

    for (int k0 = 0; k0 < CC; k0 += 64) {
        // stage A,B: 128 rows x 64 cols f32 -> bf16 swizzled LDS
        {
            const int c4 = tid & 15;          // float4 column
            int r = tid >> 4;                 // row, 16 rows/pass, 8 passes
            #pragma unroll
            for (int p = 0; p < 8; ++p, r += 16) {
                float4 va = *(const float4*)(A  + (size_t)(m0 + r) * CC + k0 + c4 * 4);
                float4 vb = *(const float4*)(Bw + (size_t)(n0 + r) * CC + k0 + c4 * 4);
                const int col = c4 * 4;                       // bf16 units
                const int idx = r * 64 + (col ^ ((r & 7) << 3));
                *(ushort4*)(&As[idx]) = make_ushort4(f2bf(va.x), f2bf(va.y), f2bf(va.z), f2bf(va.w));
                *(ushort4*)(&Bs[idx]) = make_ushort4(f2bf(vb.x), f2bf(vb.y), f2bf(vb.z), f2bf(vb.w));
            }
        }
        __syncthreads();
        #pragma unroll
        for (int kk = 0; kk < 64; kk += 32) {
            bf16x8 af[4], bfr[4];
            const int krow = lane & 15;
            const int kcol = kk + ((lane >> 4) << 3);  // bf16 units
            #pragma unroll
            for (int i = 0; i < 4; ++i) {
                const int ra = wm * 64 + i * 16 + krow;
                af[i]  = lds_read8(&As[ra * 64 + (kcol ^ ((ra & 7) << 3))]);
                const int rb = wn * 64 + i * 16 + krow;
                bfr[i] = lds_read8(&Bs[rb * 64 + (kcol ^ ((rb & 7) << 3))]);
            }
            #pragma unroll
            for (int i = 0; i < 4; ++i)
                #pragma unroll
                for (int j = 0; j < 4; ++j)
                    acc[i][j] = __builtin_amdgcn_mfma_f32_16x16x32_bf16(af[i], bfr[j], acc[i][j], 0, 0, 0);
        }
        __syncthreads();
    }

    // epilogue: + b_embed, exact gelu, * 32, store bf16
    const float* be = b_embed + (size_t)date * D_IN;
    #pragma unroll
    for (int i = 0; i < 4; ++i) {
        #pragma unroll
        for (int j = 0; j < 4; ++j) {
            const int col  = n0 + wn * 64 + j * 16 + (lane & 15);
            const float bias = be[col];
            const int rbase = m0 + wm * 64 + i * 16 + ((lane >> 4) << 2);
            #pragma unroll
            for (int q = 0; q < 4; ++q) {
                float v = acc[i][j][q] + bias;
                float g = 0.5f * v * (1.0f + erff(v * 0.70710678118654752f)) * 32.0f;
                x1[(size_t)bb * TT * D_IN + (size_t)(rbase + q) * D_IN + col] = f2bf(g);
            }
        }
    }
}

// ---------------- GEMM2: partial[ks] = stacked @ W_stack^T over K-chunk ks ----------------
// per batch M=255 (pad to 256), N=1024, K=12288 split KS ways.
// m97 structure: global_load_lds width-16 staging, linear LDS, 2-phase.
// stacked[l, s*3072+d] = x1[2l+s, d]  (gather via per-lane global source address)
template <bool WRITE_PART>
__global__ __launch_bounds__(256) void gemm2(const u16* __restrict__ x1,
                                             const u16* __restrict__ Wbf,
                                             float* __restrict__ part,
                                             const float* __restrict__ b_stack,
                                             const float* __restrict__ pos_table,
                                             const int* __restrict__ tstamp,
                                             float* __restrict__ out,
                                             int KS) {
    const int l0 = (blockIdx.x & 1) * 128;   // window row tile (0 or 128)
    const int n0 = (blockIdx.x >> 1) * 128;  // hidden col tile
    const int ks = blockIdx.y;
    const int bb = blockIdx.z;
    const int KCH  = KSTACK / KS;
    const int kbeg = ks * KCH;
    const int kend = kbeg + KCH;
    const u16* Xb = x1 + (size_t)bb * TT * D_IN;

    __shared__ u16 As[128 * 64];
    __shared__ u16 Bs[128 * 64];

    const int tid  = threadIdx.x;
    const int lane = tid & 63;
    const int wave = tid >> 6;
    const int wm = wave >> 1, wn = wave & 1;

    // staging geometry: each gload16 issue = 64 lanes * 16B = 8 rows of 64 bf16.
    // wave w covers rows [w*32, w*32+32) in 4 issues.
    const int lrow = lane >> 3;          // row within 8-row group
    const int lcol = (lane & 7) * 8;     // bf16 col within row

    f32x4 acc[4][4] = {};

    for (int k0 = kbeg; k0 < kend; k0 += 64) {
        const int s  = k0 / D_IN;        // window slot (64 | 3072, never straddles)
        const int d0 = k0 % D_IN;
        #pragma unroll
        for (int i = 0; i < 4; ++i) {
            const int rbase = wave * 32 + i * 8;
            // A: window gather. tile row -> window gl -> x1 row 2*gl+s
            int gl = l0 + rbase + lrow; if (gl > LL - 1) gl = LL - 1;
            gload16(Xb + (size_t)(2 * gl + s) * D_IN + d0 + lcol, &As[rbase * 64]);
            // B: W_stack rows
            gload16(Wbf + (size_t)(n0 + rbase + lrow) * KSTACK + k0 + lcol, &Bs[rbase * 64]);
        }
        __syncthreads();   // compiler drains vmcnt+lgkmcnt before s_barrier
        #pragma unroll
        for (int kk = 0; kk < 64; kk += 32) {
            bf16x8 af[4], bfr[4];
            const int krow = lane & 15;
            const int kcol = kk + ((lane >> 4) << 3);
            #pragma unroll
            for (int i = 0; i < 4; ++i) {
                af[i]  = lds_read8(&As[(wm * 64 + i * 16 + krow) * 64 + kcol]);
                bfr[i] = lds_read8(&Bs[(wn * 64 + i * 16 + krow) * 64 + kcol]);
            }
            #pragma unroll
            for (int i = 0; i < 4; ++i)
                #pragma unroll
                for (int j = 0; j < 4; ++j)
                    acc[i][j] = __builtin_amdgcn_mfma_f32_16x16x32_bf16(af[i], bfr[j], acc[i][j], 0, 0, 0);
        }
        __syncthreads();
    }

    if (WRITE_PART) {
        // write f32 partial tile: part[ks][bb][row 0..255][1024]
        float* pt = part + ((size_t)(ks * BATCH + bb) * 256) * HIDDEN;
        #pragma unroll
        for (int i = 0; i < 4; ++i) {
            #pragma unroll
            for (int j = 0; j < 4; ++j) {
                const int col = n0 + wn * 64 + j * 16 + (lane & 15);
                const int rb  = l0 + wm * 64 + i * 16 + ((lane >> 4) << 2);
                #pragma unroll
                for (int q = 0; q < 4; ++q)
                    pt[(size_t)(rb + q) * HIDDEN + col] = acc[i][j][q];
            }
        }
    } else {
        // direct epilogue (ws-too-small fallback): + b_stack + pos_table[ts]
        #pragma unroll
        for (int i = 0; i < 4; ++i) {
            #pragma unroll
            for (int j = 0; j < 4; ++j) {
                const int col = n0 + wn * 64 + j * 16 + (lane & 15);
                const int lb  = l0 + wm * 64 + i * 16 + ((lane >> 4) << 2);
                #pragma unroll
                for (int q = 0; q < 4; ++q) {
                    const int l = lb + q;
                    if (l < LL) {
                        const int tsv = tstamp[bb * TT + l];
                        float v = acc[i][j][q] + b_stack[col] + pos_table[(size_t)tsv * HIDDEN + col];
                        out[(size_t)bb * OUTROWS * HIDDEN + (size_t)(2 + l) * HIDDEN + col] = v;
                    }
                }
            }
        }
    }
}

// ---------------- reduce partials + bias + pos_table -> out rows 2.. ----------------
__global__ __launch_bounds__(256) void reduce_ep(const float* __restrict__ part,
                                                 const float* __restrict__ b_stack,
                                                 const float* __restrict__ pos_table,
                                                 const int* __restrict__ tstamp,
                                                 float* __restrict__ out,
                                                 int KS) {
    const int idx = blockIdx.x * 256 + threadIdx.x;          // float4 index
    const int c4  = idx & (HIDDEN / 4 - 1);
    const int r   = idx >> 8;                                // HIDDEN/4 == 256
    if (r >= BATCH * LL) return;
    const int l  = r % LL;
    const int bb = r / LL;
    float4 v = make_float4(0.f, 0.f, 0.f, 0.f);
    for (int ks = 0; ks < KS; ++ks) {
        float4 p = *(const float4*)(part + ((size_t)(ks * BATCH + bb) * 256 + l) * HIDDEN + c4 * 4);
        v.x += p.x; v.y += p.y; v.z += p.z; v.w += p.w;
    }
    const int tsv = tstamp[bb * TT + l];
    float4 bs = *(const float4*)(b_stack + c4 * 4);
    float4 ps = *(const float4*)(pos_table + (size_t)tsv * HIDDEN + c4 * 4);
    v.x += bs.x + ps.x; v.y += bs.y + ps.y; v.z += bs.z + ps.z; v.w += bs.w + ps.w;
    *(float4*)(out + ((size_t)bb * OUTROWS + 2 + l) * HIDDEN + c4 * 4) = v;
}

// ---------------- rows 0/1 + mask + ts outputs ----------------
__global__ __launch_bounds__(256) void epilogue_misc(const int* __restrict__ smask,
                                                     const int* __restrict__ tstamp,
                                                     const int* __restrict__ mask_idx_p,
                                                     const int* __restrict__ session_idx_p,
                                                     const float* __restrict__ prompt_table,
                                                     const float* __restrict__ session_table,
                                                     float* __restrict__ out) {
    const int bb = blockIdx.x;
    const int tid = threadIdx.x;
    const int mi = mask_idx_p[0];
    const int si = session_idx_p[0];
    float* xb = out + (size_t)bb * OUTROWS * HIDDEN;
    for (int i = tid; i < HIDDEN; i += 256) {
        xb[i]          = session_table[(size_t)si * HIDDEN + i];
        xb[HIDDEN + i] = prompt_table[(size_t)mi * HIDDEN + i];
    }
    float* maskout = out + (size_t)BATCH * OUTROWS * HIDDEN + (size_t)bb * OUTROWS;
    float* tsout   = out + (size_t)BATCH * OUTROWS * HIDDEN + (size_t)BATCH * OUTROWS + (size_t)bb * OUTROWS;
    for (int j = tid; j < OUTROWS; j += 256) {
        if (j == 0)      { maskout[0] = 1.0f; tsout[0] = 0.0f; }
        else if (j == 1) { maskout[1] = 1.0f; tsout[1] = 1.0f; }
        else {
            const int l = j - 2;
            int m = 1;
            #pragma unroll
            for (int s = 0; s < 4; ++s) m *= smask[bb * TT + 2 * l + s];
            maskout[j] = (float)m;
            tsout[j]   = (float)(tstamp[bb * TT + l] + 2);
        }
    }
}

extern "C" void kernel_launch(void* const* d_in, const int* in_sizes, int n_in,
                              void* d_out, int out_size, void* d_ws, size_t ws_size,
                              hipStream_t stream) {
    const float* spikes      = (const float*)d_in[0];
    const int*   spikes_mask = (const int*)d_in[1];
    const int*   tstamp      = (const int*)d_in[2];
    const int*   date_idx    = (const int*)d_in[3];
    const int*   mask_idx    = (const int*)d_in[4];
    const int*   session_idx = (const int*)d_in[5];
    const float* W_embed     = (const float*)d_in[6];
    const float* b_embed     = (const float*)d_in[7];
    const float* W_stack     = (const float*)d_in[8];
    const float* b_stack     = (const float*)d_in[9];
    const float* pos_table   = (const float*)d_in[10];
    const float* prompt_tab  = (const float*)d_in[11];
    const float* session_tab = (const float*)d_in[12];
    float* out = (float*)d_out;

    // workspace layout:
    //   x1  bf16: 16*512*3072*2           = 50,331,648 B
    //   Wbf bf16: 1024*12288*2            = 25,165,824 B
    //   part f32: KS * 16*256*1024*4      = KS * 16,777,216 B
    const size_t X1_B   = (size_t)BATCH * TT * D_IN * 2;
    const size_t WBF_B  = (size_t)HIDDEN * KSTACK * 2;
    const size_t PART_B = (size_t)BATCH * 256 * HIDDEN * 4;
    u16*   x1   = (u16*)d_ws;
    u16*   Wbf  = (u16*)((char*)d_ws + X1_B);
    float* part = (float*)((char*)d_ws + X1_B + WBF_B);

    int KS = 0;
    if      (ws_size >= X1_B + WBF_B + 3 * PART_B) KS = 3;
    else if (ws_size >= X1_B + WBF_B + 2 * PART_B) KS = 2;
    else if (ws_size >= X1_B + WBF_B + 1 * PART_B) KS = 1;

    cvt_wstack<<<2048, 256, 0, stream>>>(W_stack, Wbf);
    gemm1<<<dim3(TT / 128, D_IN / 128, BATCH), 256, 0, stream>>>(spikes, W_embed, b_embed, date_idx, x1);
    if (KS > 0) {
        gemm2<true><<<dim3(16, KS, BATCH), 256, 0, stream>>>(x1, Wbf, part, b_stack, pos_table, tstamp, out, KS);
        reduce_ep<<<(BATCH * LL * (HIDDEN / 4) + 255) / 256, 256, 0, stream>>>(part, b_stack, pos_table, tstamp, out, KS);
    } else {
        gemm2<false><<<dim3(16, 1, BATCH), 256, 0, stream>>>(x1, Wbf, part, b_stack, pos_table, tstamp, out, 1);
    }
    epilogue_misc<<<BATCH, 256, 0, stream>>>(spikes_mask, tstamp, mask_idx, session_idx,
                                             prompt_tab, session_tab, out);
}

// Round 4
// 319.585 us; speedup vs baseline: 1.1739x; 1.0629x over previous
//
#include <hip/hip_runtime.h>
#include <hip/hip_bf16.h>

// Problem constants (from reference)
#define BATCH   16
#define TT      512
#define CC      768
#define D_IN    3072
#define HIDDEN  1024
#define LL      255          // (T - 4)/2 + 1
#define OUTROWS 257
#define KSTACK  12288        // D_IN * 4

typedef float f32x4 __attribute__((ext_vector_type(4)));
typedef __bf16 bf16x8 __attribute__((ext_vector_type(8)));
typedef unsigned short u16;

// round-to-nearest-even f32 -> bf16 bits
__device__ __forceinline__ u16 f2bf(float f) {
    unsigned u = __builtin_bit_cast(unsigned, f);
    u = (u + 0x7FFFu + ((u >> 16) & 1u)) >> 16;
    return (u16)u;
}

__device__ __forceinline__ bf16x8 lds_read8(const u16* p) {
    return __builtin_bit_cast(bf16x8, *(const uint4*)p);
}

// async global->LDS, 16B per lane. LDS dest is wave-uniform base (+lane*16 by HW),
// global src is per-lane.
__device__ __forceinline__ void gload16(const u16* g, u16* l) {
    __builtin_amdgcn_global_load_lds(
        (const __attribute__((address_space(1))) void*)g,
        (__attribute__((address_space(3))) void*)l, 16, 0, 0);
}

// ---------------- W_stack f32 -> bf16 ----------------
__global__ __launch_bounds__(256) void cvt_wstack(const float* __restrict__ W, u16* __restrict__ out) {
    size_t i = ((size_t)blockIdx.x * 256 + threadIdx.x) * 4;
    size_t stride = (size_t)gridDim.x * 256 * 4;
    for (; i < (size_t)HIDDEN * KSTACK; i += stride) {
        float4 v = *(const float4*)(W + i);
        ushort4 o = make_ushort4(f2bf(v.x), f2bf(v.y), f2bf(v.z), f2bf(v.w));
        *(ushort4*)(out + i) = o;
    }
}

// ---------------- GEMM1: x1 = gelu(spikes @ W_embed[date]^T + b_embed) * 32 ----------------
// M=512, N=3072, K=768 per batch. Tile 128x128, BK=64, 4 waves (2x2), each wave 64x64.
__global__ __launch_bounds__(256) void gemm1(const float* __restrict__ spikes,
                                             const float* __restrict__ W_embed,
                                             const float* __restrict__ b_embed,
                                             const int* __restrict__ date_idx,
                                             u16* __restrict__ x1) {
    const int m0 = blockIdx.x * 128;   // t
    const int n0 = blockIdx.y * 128;   // d
    const int bb = blockIdx.z;
    const int date = date_idx[bb];
    const float* A  = spikes  + (size_t)bb  * TT * CC;
    const float* Bw = W_embed + (size_t)date * D_IN * CC;

    __shared__ u16 As[128 * 64];
    __shared__ u16 Bs[128 * 64];

    const int tid  = threadIdx.x;
    const int lane = tid & 63;
    const int wave = tid >> 6;
    const int wm = wave >> 1, wn = wave & 1;

    f32x4 acc[4][4] = {};

    for (int k0 = 0; k0 < CC; k0 += 64) {
        // stage A,B: 128 rows x 64 cols f32 -> bf16 swizzled LDS
        {
            const int c4 = tid & 15;          // float4 column
            int r = tid >> 4;                 // row, 16 rows/pass, 8 passes
            #pragma unroll
            for (int p = 0; p < 8; ++p, r += 16) {
                float4 va = *(const float4*)(A  + (size_t)(m0 + r) * CC + k0 + c4 * 4);
                float4 vb = *(const float4*)(Bw + (size_t)(n0 + r) * CC + k0 + c4 * 4);
                const int col = c4 * 4;                       // bf16 units
                const int idx = r * 64 + (col ^ ((r & 7) << 3));
                *(ushort4*)(&As[idx]) = make_ushort4(f2bf(va.x), f2bf(va.y), f2bf(va.z), f2bf(va.w));
                *(ushort4*)(&Bs[idx]) = make_ushort4(f2bf(vb.x), f2bf(vb.y), f2bf(vb.z), f2bf(vb.w));
            }
        }
        __syncthreads();
        #pragma unroll
        for (int kk = 0; kk < 64; kk += 32) {
            bf16x8 af[4], bfr[4];
            const int krow = lane & 15;
            const int kcol = kk + ((lane >> 4) << 3);  // bf16 units
            #pragma unroll
            for (int i = 0; i < 4; ++i) {
                const int ra = wm * 64 + i * 16 + krow;
                af[i]  = lds_read8(&As[ra * 64 + (kcol ^ ((ra & 7) << 3))]);
                const int rb = wn * 64 + i * 16 + krow;
                bfr[i] = lds_read8(&Bs[rb * 64 + (kcol ^ ((rb & 7) << 3))]);
            }
            #pragma unroll
            for (int i = 0; i < 4; ++i)
                #pragma unroll
                for (int j = 0; j < 4; ++j)
                    acc[i][j] = __builtin_amdgcn_mfma_f32_16x16x32_bf16(af[i], bfr[j], acc[i][j], 0, 0, 0);
        }
        __syncthreads();
    }

    // epilogue: + b_embed, exact gelu, * 32, store bf16
    const float* be = b_embed + (size_t)date * D_IN;
    #pragma unroll
    for (int i = 0; i < 4; ++i) {
        #pragma unroll
        for (int j = 0; j < 4; ++j) {
            const int col  = n0 + wn * 64 + j * 16 + (lane & 15);
            const float bias = be[col];
            const int rbase = m0 + wm * 64 + i * 16 + ((lane >> 4) << 2);
            #pragma unroll
            for (int q = 0; q < 4; ++q) {
                float v = acc[i][j][q] + bias;
                float g = 0.5f * v * (1.0f + erff(v * 0.70710678118654752f)) * 32.0f;
                x1[(size_t)bb * TT * D_IN + (size_t)(rbase + q) * D_IN + col] = f2bf(g);
            }
        }
    }
}

// ---------------- GEMM2: partial[ks] = stacked @ W_stack^T over K-chunk ks ----------------
// per batch M=255 (pad to 256), N=1024, K=12288 split KS ways.
// m97 structure: global_load_lds width-16 staging, LINEAR LDS dest, but with the
// XOR swizzle applied to the per-lane GLOBAL SOURCE address (rule 21 / m173):
// LDS ends up in st-XOR layout; fragment reads use the same involution.
// stacked[l, s*3072+d] = x1[2l+s, d]  (gather via per-lane global source address)
template <bool WRITE_PART>
__global__ __launch_bounds__(256) void gemm2(const u16* __restrict__ x1,
                                             const u16* __restrict__ Wbf,
                                             float* __restrict__ part,
                                             const float* __restrict__ b_stack,
                                             const float* __restrict__ pos_table,
                                             const int* __restrict__ tstamp,
                                             float* __restrict__ out,
                                             int KS) {
    const int l0 = (blockIdx.x & 1) * 128;   // window row tile (0 or 128)
    const int n0 = (blockIdx.x >> 1) * 128;  // hidden col tile
    const int ks = blockIdx.y;
    const int bb = blockIdx.z;
    const int KCH  = KSTACK / KS;
    const int kbeg = ks * KCH;
    const int kend = kbeg + KCH;
    const u16* Xb = x1 + (size_t)bb * TT * D_IN;

    __shared__ u16 As[128 * 64];
    __shared__ u16 Bs[128 * 64];

    const int tid  = threadIdx.x;
    const int lane = tid & 63;
    const int wave = tid >> 6;
    const int wm = wave >> 1, wn = wave & 1;

    // staging geometry: each gload16 issue = 64 lanes * 16B = 8 rows of 64 bf16.
    // wave w covers rows [w*32, w*32+32) in 4 issues.
    // lane l -> LDS (row rbase + (l>>3), col-slot (l&7)*8). To realize the st-XOR
    // layout with a linear LDS write, fetch the INVERSE-swizzled global column:
    //   scol = ((l&7) ^ (l>>3)) << 3    (row&7 == l>>3 for all issues)
    const int lrow = lane >> 3;                    // row within 8-row group
    const int scol = ((lane & 7) ^ lrow) << 3;     // pre-swizzled source col (bf16 units)

    f32x4 acc[4][4] = {};

    for (int k0 = kbeg; k0 < kend; k0 += 64) {
        const int s  = k0 / D_IN;        // window slot (64 | 3072, never straddles)
        const int d0 = k0 % D_IN;
        #pragma unroll
        for (int i = 0; i < 4; ++i) {
            const int rbase = wave * 32 + i * 8;
            // A: window gather. tile row -> window gl -> x1 row 2*gl+s
            int gl = l0 + rbase + lrow; if (gl > LL - 1) gl = LL - 1;
            gload16(Xb + (size_t)(2 * gl + s) * D_IN + d0 + scol, &As[rbase * 64]);
            // B: W_stack rows
            gload16(Wbf + (size_t)(n0 + rbase + lrow) * KSTACK + k0 + scol, &Bs[rbase * 64]);
        }
        __syncthreads();   // compiler drains vmcnt+lgkmcnt before s_barrier
        #pragma unroll
        for (int kk = 0; kk < 64; kk += 32) {
            bf16x8 af[4], bfr[4];
            const int krow = lane & 15;
            const int kcol = kk + ((lane >> 4) << 3);
            #pragma unroll
            for (int i = 0; i < 4; ++i) {
                const int ra = wm * 64 + i * 16 + krow;
                af[i]  = lds_read8(&As[ra * 64 + (kcol ^ ((ra & 7) << 3))]);
                const int rb = wn * 64 + i * 16 + krow;
                bfr[i] = lds_read8(&Bs[rb * 64 + (kcol ^ ((rb & 7) << 3))]);
            }
            #pragma unroll
            for (int i = 0; i < 4; ++i)
                #pragma unroll
                for (int j = 0; j < 4; ++j)
                    acc[i][j] = __builtin_amdgcn_mfma_f32_16x16x32_bf16(af[i], bfr[j], acc[i][j], 0, 0, 0);
        }
        __syncthreads();
    }

    if (WRITE_PART) {
        // write f32 partial tile: part[ks][bb][row 0..255][1024]
        float* pt = part + ((size_t)(ks * BATCH + bb) * 256) * HIDDEN;
        #pragma unroll
        for (int i = 0; i < 4; ++i) {
            #pragma unroll
            for (int j = 0; j < 4; ++j) {
                const int col = n0 + wn * 64 + j * 16 + (lane & 15);
                const int rb  = l0 + wm * 64 + i * 16 + ((lane >> 4) << 2);
                #pragma unroll
                for (int q = 0; q < 4; ++q)
                    pt[(size_t)(rb + q) * HIDDEN + col] = acc[i][j][q];
            }
        }
    } else {
        // direct epilogue (ws-too-small fallback): + b_stack + pos_table[ts]
        #pragma unroll
        for (int i = 0; i < 4; ++i) {
            #pragma unroll
            for (int j = 0; j < 4; ++j) {
                const int col = n0 + wn * 64 + j * 16 + (lane & 15);
                const int lb  = l0 + wm * 64 + i * 16 + ((lane >> 4) << 2);
                #pragma unroll
                for (int q = 0; q < 4; ++q) {
                    const int l = lb + q;
                    if (l < LL) {
                        const int tsv = tstamp[bb * TT + l];
                        float v = acc[i][j][q] + b_stack[col] + pos_table[(size_t)tsv * HIDDEN + col];
                        out[(size_t)bb * OUTROWS * HIDDEN + (size_t)(2 + l) * HIDDEN + col] = v;
                    }
                }
            }
        }
    }
}

// ---------------- reduce partials + bias + pos_table -> out rows 2.. ----------------
__global__ __launch_bounds__(256) void reduce_ep(const float* __restrict__ part,
                                                 const float* __restrict__ b_stack,
                                                 const float* __restrict__ pos_table,
                                                 const int* __restrict__ tstamp,
                                                 float* __restrict__ out,
                                                 int KS) {
    const int idx = blockIdx.x * 256 + threadIdx.x;          // float4 index
    const int c4  = idx & (HIDDEN / 4 - 1);
    const int r   = idx >> 8;                                // HIDDEN/4 == 256
    if (r >= BATCH * LL) return;
    const int l  = r % LL;
    const int bb = r / LL;
    float4 v = make_float4(0.f, 0.f, 0.f, 0.f);
    for (int ks = 0; ks < KS; ++ks) {
        float4 p = *(const float4*)(part + ((size_t)(ks * BATCH + bb) * 256 + l) * HIDDEN + c4 * 4);
        v.x += p.x; v.y += p.y; v.z += p.z; v.w += p.w;
    }
    const int tsv = tstamp[bb * TT + l];
    float4 bs = *(const float4*)(b_stack + c4 * 4);
    float4 ps = *(const float4*)(pos_table + (size_t)tsv * HIDDEN + c4 * 4);
    v.x += bs.x + ps.x; v.y += bs.y + ps.y; v.z += bs.z + ps.z; v.w += bs.w + ps.w;
    *(float4*)(out + ((size_t)bb * OUTROWS + 2 + l) * HIDDEN + c4 * 4) = v;
}

// ---------------- rows 0/1 + mask + ts outputs ----------------
__global__ __launch_bounds__(256) void epilogue_misc(const int* __restrict__ smask,
                                                     const int* __restrict__ tstamp,
                                                     const int* __restrict__ mask_idx_p,
                                                     const int* __restrict__ session_idx_p,
                                                     const float* __restrict__ prompt_table,
                                                     const float* __restrict__ session_table,
                                                     float* __restrict__ out) {
    const int bb = blockIdx.x;
    const int tid = threadIdx.x;
    const int mi = mask_idx_p[0];
    const int si = session_idx_p[0];
    float* xb = out + (size_t)bb * OUTROWS * HIDDEN;
    for (int i = tid; i < HIDDEN; i += 256) {
        xb[i]          = session_table[(size_t)si * HIDDEN + i];
        xb[HIDDEN + i] = prompt_table[(size_t)mi * HIDDEN + i];
    }
    float* maskout = out + (size_t)BATCH * OUTROWS * HIDDEN + (size_t)bb * OUTROWS;
    float* tsout   = out + (size_t)BATCH * OUTROWS * HIDDEN + (size_t)BATCH * OUTROWS + (size_t)bb * OUTROWS;
    for (int j = tid; j < OUTROWS; j += 256) {
        if (j == 0)      { maskout[0] = 1.0f; tsout[0] = 0.0f; }
        else if (j == 1) { maskout[1] = 1.0f; tsout[1] = 1.0f; }
        else {
            const int l = j - 2;
            int m = 1;
            #pragma unroll
            for (int s = 0; s < 4; ++s) m *= smask[bb * TT + 2 * l + s];
            maskout[j] = (float)m;
            tsout[j]   = (float)(tstamp[bb * TT + l] + 2);
        }
    }
}

extern "C" void kernel_launch(void* const* d_in, const int* in_sizes, int n_in,
                              void* d_out, int out_size, void* d_ws, size_t ws_size,
                              hipStream_t stream) {
    const float* spikes      = (const float*)d_in[0];
    const int*   spikes_mask = (const int*)d_in[1];
    const int*   tstamp      = (const int*)d_in[2];
    const int*   date_idx    = (const int*)d_in[3];
    const int*   mask_idx    = (const int*)d_in[4];
    const int*   session_idx = (const int*)d_in[5];
    const float* W_embed     = (const float*)d_in[6];
    const float* b_embed     = (const float*)d_in[7];
    const float* W_stack     = (const float*)d_in[8];
    const float* b_stack     = (const float*)d_in[9];
    const float* pos_table   = (const float*)d_in[10];
    const float* prompt_tab  = (const float*)d_in[11];
    const float* session_tab = (const float*)d_in[12];
    float* out = (float*)d_out;

    // workspace layout:
    //   x1  bf16: 16*512*3072*2           = 50,331,648 B
    //   Wbf bf16: 1024*12288*2            = 25,165,824 B
    //   part f32: KS * 16*256*1024*4      = KS * 16,777,216 B
    const size_t X1_B   = (size_t)BATCH * TT * D_IN * 2;
    const size_t WBF_B  = (size_t)HIDDEN * KSTACK * 2;
    const size_t PART_B = (size_t)BATCH * 256 * HIDDEN * 4;
    u16*   x1   = (u16*)d_ws;
    u16*   Wbf  = (u16*)((char*)d_ws + X1_B);
    float* part = (float*)((char*)d_ws + X1_B + WBF_B);

    int KS = 0;
    if      (ws_size >= X1_B + WBF_B + 3 * PART_B) KS = 3;
    else if (ws_size >= X1_B + WBF_B + 2 * PART_B) KS = 2;
    else if (ws_size >= X1_B + WBF_B + 1 * PART_B) KS = 1;

    cvt_wstack<<<2048, 256, 0, stream>>>(W_stack, Wbf);
    gemm1<<<dim3(TT / 128, D_IN / 128, BATCH), 256, 0, stream>>>(spikes, W_embed, b_embed, date_idx, x1);
    if (KS > 0) {
        gemm2<true><<<dim3(16, KS, BATCH), 256, 0, stream>>>(x1, Wbf, part, b_stack, pos_table, tstamp, out, KS);
        reduce_ep<<<(BATCH * LL * (HIDDEN / 4) + 255) / 256, 256, 0, stream>>>(part, b_stack, pos_table, tstamp, out, KS);
    } else {
        gemm2<false><<<dim3(16, 1, BATCH), 256, 0, stream>>>(x1, Wbf, part, b_stack, pos_table, tstamp, out, 1);
    }
    epilogue_misc<<<BATCH, 256, 0, stream>>>(spikes_mask, tstamp, mask_idx, session_idx,
                                             prompt_tab, session_tab, out);
}

// Round 5
// 262.789 us; speedup vs baseline: 1.4276x; 1.2161x over previous
//
#include <hip/hip_runtime.h>
#include <hip/hip_bf16.h>

// Problem constants (from reference)
#define BATCH   16
#define TT      512
#define CC      768
#define D_IN    3072
#define HIDDEN  1024
#define LL      255          // (T - 4)/2 + 1
#define OUTROWS 257
#define KSTACK  12288        // D_IN * 4

typedef float f32x4 __attribute__((ext_vector_type(4)));
typedef __bf16 bf16x8 __attribute__((ext_vector_type(8)));
typedef unsigned short u16;

// round-to-nearest-even f32 -> bf16 bits
__device__ __forceinline__ u16 f2bf(float f) {
    unsigned u = __builtin_bit_cast(unsigned, f);
    u = (u + 0x7FFFu + ((u >> 16) & 1u)) >> 16;
    return (u16)u;
}

__device__ __forceinline__ bf16x8 lds_read8(const u16* p) {
    return __builtin_bit_cast(bf16x8, *(const uint4*)p);
}

// async global->LDS, 16B per lane. LDS dest is wave-uniform base (+lane*16 by HW),
// global src is per-lane.
__device__ __forceinline__ void gload16(const u16* g, u16* l) {
    __builtin_amdgcn_global_load_lds(
        (const __attribute__((address_space(1))) void*)g,
        (__attribute__((address_space(3))) void*)l, 16, 0, 0);
}

// ---------------- W_stack f32 -> bf16 ----------------
__global__ __launch_bounds__(256) void cvt_wstack(const float* __restrict__ W, u16* __restrict__ out) {
    size_t i = ((size_t)blockIdx.x * 256 + threadIdx.x) * 4;
    size_t stride = (size_t)gridDim.x * 256 * 4;
    for (; i < (size_t)HIDDEN * KSTACK; i += stride) {
        float4 v = *(const float4*)(W + i);
        ushort4 o = make_ushort4(f2bf(v.x), f2bf(v.y), f2bf(v.z), f2bf(v.w));
        *(ushort4*)(out + i) = o;
    }
}

// ---------------- GEMM1: x1 = gelu(spikes @ W_embed[date]^T + b_embed) * 32 ----------------
// M=512, N=3072, K=768 per batch. Tile 128x128, BK=64, 4 waves (2x2), each wave 64x64.
__global__ __launch_bounds__(256) void gemm1(const float* __restrict__ spikes,
                                             const float* __restrict__ W_embed,
                                             const float* __restrict__ b_embed,
                                             const int* __restrict__ date_idx,
                                             u16* __restrict__ x1) {
    const int m0 = blockIdx.x * 128;   // t
    const int n0 = blockIdx.y * 128;   // d
    const int bb = blockIdx.z;
    const int date = date_idx[bb];
    const float* A  = spikes  + (size_t)bb  * TT * CC;
    const float* Bw = W_embed + (size_t)date * D_IN * CC;

    __shared__ u16 As[128 * 64];
    __shared__ u16 Bs[128 * 64];

    const int tid  = threadIdx.x;
    const int lane = tid & 63;
    const int wave = tid >> 6;
    const int wm = wave >> 1, wn = wave & 1;

    f32x4 acc[4][4] = {};

    for (int k0 = 0; k0 < CC; k0 += 64) {
        // stage A,B: 128 rows x 64 cols f32 -> bf16 swizzled LDS
        {
            const int c4 = tid & 15;          // float4 column
            int r = tid >> 4;                 // row, 16 rows/pass, 8 passes
            #pragma unroll
            for (int p = 0; p < 8; ++p, r += 16) {
                float4 va = *(const float4*)(A  + (size_t)(m0 + r) * CC + k0 + c4 * 4);
                float4 vb = *(const float4*)(Bw + (size_t)(n0 + r) * CC + k0 + c4 * 4);
                const int col = c4 * 4;                       // bf16 units
                const int idx = r * 64 + (col ^ ((r & 7) << 3));
                *(ushort4*)(&As[idx]) = make_ushort4(f2bf(va.x), f2bf(va.y), f2bf(va.z), f2bf(va.w));
                *(ushort4*)(&Bs[idx]) = make_ushort4(f2bf(vb.x), f2bf(vb.y), f2bf(vb.z), f2bf(vb.w));
            }
        }
        __syncthreads();
        #pragma unroll
        for (int kk = 0; kk < 64; kk += 32) {
            bf16x8 af[4], bfr[4];
            const int krow = lane & 15;
            const int kcol = kk + ((lane >> 4) << 3);  // bf16 units
            #pragma unroll
            for (int i = 0; i < 4; ++i) {
                const int ra = wm * 64 + i * 16 + krow;
                af[i]  = lds_read8(&As[ra * 64 + (kcol ^ ((ra & 7) << 3))]);
                const int rb = wn * 64 + i * 16 + krow;
                bfr[i] = lds_read8(&Bs[rb * 64 + (kcol ^ ((rb & 7) << 3))]);
            }
            #pragma unroll
            for (int i = 0; i < 4; ++i)
                #pragma unroll
                for (int j = 0; j < 4; ++j)
                    acc[i][j] = __builtin_amdgcn_mfma_f32_16x16x32_bf16(af[i], bfr[j], acc[i][j], 0, 0, 0);
        }
        __syncthreads();
    }

    // epilogue: + b_embed, exact gelu, * 32, store bf16
    const float* be = b_embed + (size_t)date * D_IN;
    #pragma unroll
    for (int i = 0; i < 4; ++i) {
        #pragma unroll
        for (int j = 0; j < 4; ++j) {
            const int col  = n0 + wn * 64 + j * 16 + (lane & 15);
            const float bias = be[col];
            const int rbase = m0 + wm * 64 + i * 16 + ((lane >> 4) << 2);
            #pragma unroll
            for (int q = 0; q < 4; ++q) {
                float v = acc[i][j][q] + bias;
                float g = 0.5f * v * (1.0f + erff(v * 0.70710678118654752f)) * 32.0f;
                x1[(size_t)bb * TT * D_IN + (size_t)(rbase + q) * D_IN + col] = f2bf(g);
            }
        }
    }
}

// ---------------- GEMM2: 256x256 tile, 8 waves, 2-deep counted-vmcnt pipeline ----------------
// per batch M=255 (pad 256), N=1024 (4 tiles of 256), K=12288 split KS ways.
// Double-buffered LDS (128 KiB); global_load_lds w16 with source-XOR swizzle (rule 21);
// raw s_barrier + counted vmcnt(8): next K-step's 8 loads stay in flight across barriers.
// stacked[l, s*3072+d] = x1[2l+s, d]
template <bool WRITE_PART>
__global__ __launch_bounds__(512, 2) void gemm2(const u16* __restrict__ x1,
                                                const u16* __restrict__ Wbf,
                                                float* __restrict__ part,
                                                const float* __restrict__ b_stack,
                                                const float* __restrict__ pos_table,
                                                const int* __restrict__ tstamp,
                                                float* __restrict__ out,
                                                int KS) {
    const int n0 = blockIdx.x * 256;   // hidden col tile (0..3)
    const int ks = blockIdx.y;
    const int bb = blockIdx.z;
    const int KCH  = KSTACK / KS;
    const int kbeg = ks * KCH;
    const int nt   = KCH / 64;         // K-steps
    const u16* Xb = x1 + (size_t)bb * TT * D_IN;

    __shared__ u16 Asm[2 * 256 * 64];  // 64 KiB
    __shared__ u16 Bsm[2 * 256 * 64];  // 64 KiB

    const int tid  = threadIdx.x;
    const int lane = tid & 63;
    const int wave = tid >> 6;         // 0..7
    const int wm = wave >> 2;          // 0..1 (M half)
    const int wn = wave & 3;           // 0..3 (N quarter)

    // staging geometry: per wave-issue, 64 lanes x 16B = 8 rows x 64 cols.
    // lane l -> LDS (row rbase+(l>>3), col-slot (l&7)*8). Inverse-swizzled source col:
    const int lrow = lane >> 3;                    // row within 8-row group
    const int scol = ((lane & 7) ^ lrow) << 3;     // pre-swizzled source col (bf16 units)

    f32x4 acc[8][4] = {};

    // STAGE one K-step (k0) into buffer `buf`: 4 A-issues + 4 B-issues per wave
    auto STAGE = [&](int k0, int buf) {
        const int s  = k0 / D_IN;      // window slot (never straddles: 3072 % 64 == 0)
        const int d0 = k0 % D_IN;
        u16* Ad = Asm + buf * (256 * 64);
        u16* Bd = Bsm + buf * (256 * 64);
        #pragma unroll
        for (int i = 0; i < 4; ++i) {
            const int rb = i * 8 + wave;           // row-block 0..31 (8 rows each)
            const int row = rb * 8 + lrow;         // 0..255
            int gl = row; if (gl > LL - 1) gl = LL - 1;
            gload16(Xb + (size_t)(2 * gl + s) * D_IN + d0 + scol, Ad + rb * 512);
            gload16(Wbf + (size_t)(n0 + row) * KSTACK + k0 + scol, Bd + rb * 512);
        }
    };

    // prologue: fill both buffers (16 loads in flight per wave)
    STAGE(kbeg, 0);
    STAGE(kbeg + 64, 1);

    for (int t = 0; t < nt; ++t) {
        const int cur = t & 1;
        // wait for buf[cur]'s 8 loads (the oldest); leave next step's 8 in flight
        if (t + 1 < nt) { asm volatile("s_waitcnt vmcnt(8)" ::: "memory"); }
        else            { asm volatile("s_waitcnt vmcnt(0)" ::: "memory"); }
        __builtin_amdgcn_s_barrier();              // publish all waves' DMA writes
        asm volatile("" ::: "memory");

        const u16* Ab = Asm + cur * (256 * 64);
        const u16* Bb = Bsm + cur * (256 * 64);
        #pragma unroll
        for (int kk = 0; kk < 64; kk += 32) {
            bf16x8 af[8], bfr[4];
            const int krow = lane & 15;
            const int kcol = kk + ((lane >> 4) << 3);
            #pragma unroll
            for (int i = 0; i < 8; ++i) {
                const int ra = wm * 128 + i * 16 + krow;
                af[i] = lds_read8(&Ab[ra * 64 + (kcol ^ ((ra & 7) << 3))]);
            }
            #pragma unroll
            for (int j = 0; j < 4; ++j) {
                const int rb2 = wn * 64 + j * 16 + krow;
                bfr[j] = lds_read8(&Bb[rb2 * 64 + (kcol ^ ((rb2 & 7) << 3))]);
            }
            #pragma unroll
            for (int i = 0; i < 8; ++i)
                #pragma unroll
                for (int j = 0; j < 4; ++j)
                    acc[i][j] = __builtin_amdgcn_mfma_f32_16x16x32_bf16(af[i], bfr[j], acc[i][j], 0, 0, 0);
        }

        asm volatile("" ::: "memory");
        __builtin_amdgcn_s_barrier();              // all waves done reading buf[cur]
        asm volatile("" ::: "memory");
        if (t + 2 < nt) STAGE(kbeg + (t + 2) * 64, cur);   // restage freed buffer
    }

    if (WRITE_PART) {
        // write f32 partial tile: part[ks][bb][row 0..255][1024]
        float* pt = part + ((size_t)(ks * BATCH + bb) * 256) * HIDDEN;
        #pragma unroll
        for (int i = 0; i < 8; ++i) {
            #pragma unroll
            for (int j = 0; j < 4; ++j) {
                const int col = n0 + wn * 64 + j * 16 + (lane & 15);
                const int rb  = wm * 128 + i * 16 + ((lane >> 4) << 2);
                #pragma unroll
                for (int q = 0; q < 4; ++q)
                    pt[(size_t)(rb + q) * HIDDEN + col] = acc[i][j][q];
            }
        }
    } else {
        // direct epilogue (ws-too-small fallback): + b_stack + pos_table[ts]
        #pragma unroll
        for (int i = 0; i < 8; ++i) {
            #pragma unroll
            for (int j = 0; j < 4; ++j) {
                const int col = n0 + wn * 64 + j * 16 + (lane & 15);
                const int lb  = wm * 128 + i * 16 + ((lane >> 4) << 2);
                #pragma unroll
                for (int q = 0; q < 4; ++q) {
                    const int l = lb + q;
                    if (l < LL) {
                        const int tsv = tstamp[bb * TT + l];
                        float v = acc[i][j][q] + b_stack[col] + pos_table[(size_t)tsv * HIDDEN + col];
                        out[(size_t)bb * OUTROWS * HIDDEN + (size_t)(2 + l) * HIDDEN + col] = v;
                    }
                }
            }
        }
    }
}

// ---------------- reduce partials + bias + pos_table -> out rows 2.. ----------------
__global__ __launch_bounds__(256) void reduce_ep(const float* __restrict__ part,
                                                 const float* __restrict__ b_stack,
                                                 const float* __restrict__ pos_table,
                                                 const int* __restrict__ tstamp,
                                                 float* __restrict__ out,
                                                 int KS) {
    const int idx = blockIdx.x * 256 + threadIdx.x;          // float4 index
    const int c4  = idx & (HIDDEN / 4 - 1);
    const int r   = idx >> 8;                                // HIDDEN/4 == 256
    if (r >= BATCH * LL) return;
    const int l  = r % LL;
    const int bb = r / LL;
    float4 v = make_float4(0.f, 0.f, 0.f, 0.f);
    for (int ks = 0; ks < KS; ++ks) {
        float4 p = *(const float4*)(part + ((size_t)(ks * BATCH + bb) * 256 + l) * HIDDEN + c4 * 4);
        v.x += p.x; v.y += p.y; v.z += p.z; v.w += p.w;
    }
    const int tsv = tstamp[bb * TT + l];
    float4 bs = *(const float4*)(b_stack + c4 * 4);
    float4 ps = *(const float4*)(pos_table + (size_t)tsv * HIDDEN + c4 * 4);
    v.x += bs.x + ps.x; v.y += bs.y + ps.y; v.z += bs.z + ps.z; v.w += bs.w + ps.w;
    *(float4*)(out + ((size_t)bb * OUTROWS + 2 + l) * HIDDEN + c4 * 4) = v;
}

// ---------------- rows 0/1 + mask + ts outputs ----------------
__global__ __launch_bounds__(256) void epilogue_misc(const int* __restrict__ smask,
                                                     const int* __restrict__ tstamp,
                                                     const int* __restrict__ mask_idx_p,
                                                     const int* __restrict__ session_idx_p,
                                                     const float* __restrict__ prompt_table,
                                                     const float* __restrict__ session_table,
                                                     float* __restrict__ out) {
    const int bb = blockIdx.x;
    const int tid = threadIdx.x;
    const int mi = mask_idx_p[0];
    const int si = session_idx_p[0];
    float* xb = out + (size_t)bb * OUTROWS * HIDDEN;
    for (int i = tid; i < HIDDEN; i += 256) {
        xb[i]          = session_table[(size_t)si * HIDDEN + i];
        xb[HIDDEN + i] = prompt_table[(size_t)mi * HIDDEN + i];
    }
    float* maskout = out + (size_t)BATCH * OUTROWS * HIDDEN + (size_t)bb * OUTROWS;
    float* tsout   = out + (size_t)BATCH * OUTROWS * HIDDEN + (size_t)BATCH * OUTROWS + (size_t)bb * OUTROWS;
    for (int j = tid; j < OUTROWS; j += 256) {
        if (j == 0)      { maskout[0] = 1.0f; tsout[0] = 0.0f; }
        else if (j == 1) { maskout[1] = 1.0f; tsout[1] = 1.0f; }
        else {
            const int l = j - 2;
            int m = 1;
            #pragma unroll
            for (int s = 0; s < 4; ++s) m *= smask[bb * TT + 2 * l + s];
            maskout[j] = (float)m;
            tsout[j]   = (float)(tstamp[bb * TT + l] + 2);
        }
    }
}

extern "C" void kernel_launch(void* const* d_in, const int* in_sizes, int n_in,
                              void* d_out, int out_size, void* d_ws, size_t ws_size,
                              hipStream_t stream) {
    const float* spikes      = (const float*)d_in[0];
    const int*   spikes_mask = (const int*)d_in[1];
    const int*   tstamp      = (const int*)d_in[2];
    const int*   date_idx    = (const int*)d_in[3];
    const int*   mask_idx    = (const int*)d_in[4];
    const int*   session_idx = (const int*)d_in[5];
    const float* W_embed     = (const float*)d_in[6];
    const float* b_embed     = (const float*)d_in[7];
    const float* W_stack     = (const float*)d_in[8];
    const float* b_stack     = (const float*)d_in[9];
    const float* pos_table   = (const float*)d_in[10];
    const float* prompt_tab  = (const float*)d_in[11];
    const float* session_tab = (const float*)d_in[12];
    float* out = (float*)d_out;

    // workspace layout:
    //   x1  bf16: 16*512*3072*2           = 50,331,648 B
    //   Wbf bf16: 1024*12288*2            = 25,165,824 B
    //   part f32: KS * 16*256*1024*4      = KS * 16,777,216 B
    const size_t X1_B   = (size_t)BATCH * TT * D_IN * 2;
    const size_t WBF_B  = (size_t)HIDDEN * KSTACK * 2;
    const size_t PART_B = (size_t)BATCH * 256 * HIDDEN * 4;
    u16*   x1   = (u16*)d_ws;
    u16*   Wbf  = (u16*)((char*)d_ws + X1_B);
    float* part = (float*)((char*)d_ws + X1_B + WBF_B);

    int KS = 0;
    if      (ws_size >= X1_B + WBF_B + 4 * PART_B) KS = 4;
    else if (ws_size >= X1_B + WBF_B + 3 * PART_B) KS = 3;
    else if (ws_size >= X1_B + WBF_B + 2 * PART_B) KS = 2;
    else if (ws_size >= X1_B + WBF_B + 1 * PART_B) KS = 1;

    cvt_wstack<<<2048, 256, 0, stream>>>(W_stack, Wbf);
    gemm1<<<dim3(TT / 128, D_IN / 128, BATCH), 256, 0, stream>>>(spikes, W_embed, b_embed, date_idx, x1);
    if (KS > 0) {
        gemm2<true><<<dim3(HIDDEN / 256, KS, BATCH), 512, 0, stream>>>(x1, Wbf, part, b_stack, pos_table, tstamp, out, KS);
        reduce_ep<<<(BATCH * LL * (HIDDEN / 4) + 255) / 256, 256, 0, stream>>>(part, b_stack, pos_table, tstamp, out, KS);
    } else {
        gemm2<false><<<dim3(HIDDEN / 256, 1, BATCH), 512, 0, stream>>>(x1, Wbf, part, b_stack, pos_table, tstamp, out, 1);
    }
    epilogue_misc<<<BATCH, 256, 0, stream>>>(spikes_mask, tstamp, mask_idx, session_idx,
                                             prompt_tab, session_tab, out);
}